// Round 2
// baseline (6720.046 us; speedup 1.0000x reference)
//
#include <hip/hip_runtime.h>
#include <cstdint>
#include <cstddef>

// Sizes (hardcoded per reference)
static constexpr int H     = 512;    // hidden
static constexpr int WD    = 1024;   // word dim
static constexpr int NV    = 30000;  // vocab
static constexpr int NB    = 64;     // batch
static constexpr int NS    = 256;    // encoder seq len
static constexpr int NSTEP = 27;     // T-1 decode steps
static constexpr int G4    = 2048;   // 4*H

// float -> order-preserving uint key
__device__ __forceinline__ unsigned fkey(float f) {
  unsigned u = __float_as_uint(f);
  return u ^ (0x80000000u | (unsigned)((int)u >> 31));
}

// ---------------------------------------------------------------------------
// Kernel A: u_e = W1[:H] @ W2 @ W3 @ Wv   (attention MLP collapsed to a vector;
// biases + h-term cancel in softmax over s). One block, 512 threads.
// ---------------------------------------------------------------------------
__global__ __launch_bounds__(512) void k_ue(
    const float* __restrict__ W1, const float* __restrict__ W2,
    const float* __restrict__ W3, const float* __restrict__ Wv,
    float* __restrict__ ue) {
  __shared__ float wv[H], t1[H], t2[H];
  const int tid = threadIdx.x;
  wv[tid] = Wv[tid];
  __syncthreads();
  {
    const float4* row = (const float4*)(W3 + (size_t)tid * H);
    float a = 0.f;
#pragma unroll 4
    for (int j = 0; j < H / 4; ++j) {
      float4 w = row[j];
      a += w.x * wv[4 * j] + w.y * wv[4 * j + 1] + w.z * wv[4 * j + 2] + w.w * wv[4 * j + 3];
    }
    t1[tid] = a;
  }
  __syncthreads();
  {
    const float4* row = (const float4*)(W2 + (size_t)tid * H);
    float a = 0.f;
#pragma unroll 4
    for (int j = 0; j < H / 4; ++j) {
      float4 w = row[j];
      a += w.x * t1[4 * j] + w.y * t1[4 * j + 1] + w.z * t1[4 * j + 2] + w.w * t1[4 * j + 3];
    }
    t2[tid] = a;
  }
  __syncthreads();
  {
    const float4* row = (const float4*)(W1 + (size_t)tid * H);  // rows 0..511 = enc part
    float a = 0.f;
#pragma unroll 4
    for (int j = 0; j < H / 4; ++j) {
      float4 w = row[j];
      a += w.x * t2[4 * j] + w.y * t2[4 * j + 1] + w.z * t2[4 * j + 2] + w.w * t2[4 * j + 3];
    }
    ue[tid] = a;
  }
}

// ---------------------------------------------------------------------------
// Kernel B: per batch b: score[s] = enc[b,s,:]·u_e ; aw = softmax_s(score);
// ctx[b,:] = sum_s aw[s]*enc[b,s,:].  Time-invariant. 64 blocks x 256 threads.
// ---------------------------------------------------------------------------
__global__ __launch_bounds__(256) void k_attn(
    const float* __restrict__ enc, const float* __restrict__ ue,
    float* __restrict__ ctx) {
  __shared__ float uel[H];
  __shared__ float sc[NS];
  __shared__ float red[NS];
  const int b = blockIdx.x;
  const int tid = threadIdx.x;
  uel[tid] = ue[tid];
  uel[tid + 256] = ue[tid + 256];
  __syncthreads();
  float acc = 0.f;
  {
    const float4* row = (const float4*)(enc + ((size_t)b * NS + tid) * H);
#pragma unroll 4
    for (int j = 0; j < H / 4; ++j) {
      float4 e = row[j];
      acc += e.x * uel[4 * j] + e.y * uel[4 * j + 1] + e.z * uel[4 * j + 2] + e.w * uel[4 * j + 3];
    }
  }
  red[tid] = acc;
  __syncthreads();
  for (int s = 128; s > 0; s >>= 1) {
    if (tid < s) red[tid] = fmaxf(red[tid], red[tid + s]);
    __syncthreads();
  }
  const float mx = red[0];
  __syncthreads();
  const float ex = expf(acc - mx);
  red[tid] = ex;
  __syncthreads();
  for (int s = 128; s > 0; s >>= 1) {
    if (tid < s) red[tid] += red[tid + s];
    __syncthreads();
  }
  const float inv = 1.f / red[0];
  sc[tid] = ex * inv;
  __syncthreads();
  for (int h0 = 0; h0 < H; h0 += 256) {
    const int hh = h0 + tid;
    float a = 0.f;
    for (int s = 0; s < NS; ++s) a += sc[s] * enc[((size_t)b * NS + s) * H + hh];
    ctx[b * H + hh] = a;
  }
}

// ---------------------------------------------------------------------------
// Kernel B2: gctx[b,k] = bih[k]+bhh[k] + sum_j ctx[b,j]*Wih[WD+j, k]
// (time-invariant part of the LSTM pre-activation). 64 blocks x 256 threads.
// ---------------------------------------------------------------------------
__global__ __launch_bounds__(256) void k_gctx(
    const float* __restrict__ Wih, const float* __restrict__ bih,
    const float* __restrict__ bhh, const float* __restrict__ ctx,
    float* __restrict__ gctx) {
  __shared__ float cl[8 * H];
  const int tid = threadIdx.x;
  const int kx = blockIdx.x & 7, bg = blockIdx.x >> 3;
  const int k = kx * 256 + tid;
  for (int i = tid; i < 8 * H; i += 256) cl[i] = ctx[(size_t)bg * 8 * H + i];
  __syncthreads();
  float acc[8];
  const float bias = bih[k] + bhh[k];
#pragma unroll
  for (int r = 0; r < 8; ++r) acc[r] = bias;
  const float* wp = Wih + (size_t)WD * G4 + k;
  for (int j = 0; j < H; ++j) {
    float w = wp[(size_t)j * G4];
#pragma unroll
    for (int r = 0; r < 8; ++r) acc[r] += cl[r * H + j] * w;
  }
#pragma unroll
  for (int r = 0; r < 8; ++r) gctx[(size_t)(bg * 8 + r) * G4 + k] = acc[r];
}

// ---------------------------------------------------------------------------
// Kernel C (per step): gates = [emb[ciw]]@Wih_top + h@Whh + gctx, LSTM pointwise.
// 256 blocks (i-strips of 2) x 256 threads. Block 0 also zeroes packed[t] and
// writes prediction t-1 (fp32) to d_out.
// ---------------------------------------------------------------------------
__global__ __launch_bounds__(256) void k_step(
    const float* __restrict__ emb, const float* __restrict__ Wih,
    const float* __restrict__ Whh, const float* __restrict__ gctx,
    const float* __restrict__ hin, float* __restrict__ hout,
    float* __restrict__ cbuf,
    const unsigned long long* __restrict__ packedPrev,
    unsigned long long* __restrict__ packedCur,
    float* __restrict__ pred, int step) {
  __shared__ float Xt[128 * 64];   // [jj][b]
  __shared__ float4 ps4[256];
  const int tid = threadIdx.x;
  const int b = tid & 63;
  const int q = tid >> 6;          // 0..3
  const int il = q & 1, jh = q >> 1;
  const int i = blockIdx.x * 2 + il;

  int ciw = 1;  // <BOS> at step 0
  if (step > 0) {
    unsigned long long kp = packedPrev[b];
    ciw = 0x7FFFFFFF - (int)(unsigned)(kp & 0xFFFFFFFFull);
  }
  if (blockIdx.x == 0 && tid < NB) {
    packedCur[tid] = 0ull;  // init argmax accumulator for this step
    if (step > 0) {
      unsigned long long kp = packedPrev[tid];
      int v = 0x7FFFFFFF - (int)(unsigned)(kp & 0xFFFFFFFFull);
      pred[tid * NSTEP + (step - 1)] = (float)v;
    }
  }
  const float* __restrict__ embrow = emb + (size_t)ciw * WD;
  float a0 = 0.f, a1 = 0.f, a2 = 0.f, a3 = 0.f;

  for (int tile = 0; tile < 12; ++tile) {
    const int jbase = tile * 128;
    __syncthreads();
    if (jbase < WD) {  // embedding part (tiles 0..7)
#pragma unroll
      for (int k = 0; k < 32; ++k) {
        int jj = k * 4 + q;
        Xt[jj * 64 + b] = embrow[jbase + jj];
      }
    } else {           // hidden-state part (tiles 8..11)
#pragma unroll
      for (int k = 0; k < 32; ++k) {
        int jj = k * 4 + q;
        Xt[jj * 64 + b] = hin[b * H + (jbase - WD + jj)];
      }
    }
    __syncthreads();
    const float* wr = ((jbase < WD) ? (Wih + (size_t)(jbase + jh * 64) * G4)
                                    : (Whh + (size_t)(jbase - WD + jh * 64) * G4)) + i;
    const float* xp = &Xt[(jh * 64) * 64 + b];
#pragma unroll 4
    for (int jj = 0; jj < 64; ++jj) {
      float x = xp[jj * 64];
      a0 += x * wr[0];
      a1 += x * wr[512];
      a2 += x * wr[1024];
      a3 += x * wr[1536];
      wr += G4;
    }
  }
  ps4[tid] = make_float4(a0, a1, a2, a3);
  __syncthreads();
  if (tid < 128) {  // jh==0 threads own (b, i): combine halves + LSTM update
    float4 m = ps4[tid];
    float4 o = ps4[tid + 128];
    const float* gb = gctx + (size_t)b * G4 + i;
    float gi = m.x + o.x + gb[0];
    float gf = m.y + o.y + gb[512];
    float gg = m.z + o.z + gb[1024];
    float go = m.w + o.w + gb[1536];
    float cp = (step == 0) ? 0.f : cbuf[b * H + i];
    float si = 1.f / (1.f + expf(-gi));
    float sf = 1.f / (1.f + expf(-gf));
    float so = 1.f / (1.f + expf(-go));
    float cn = sf * cp + si * tanhf(gg);
    float hn = so * tanhf(cn);
    cbuf[b * H + i] = cn;
    hout[b * H + i] = hn;
  }
}

// ---------------------------------------------------------------------------
// Kernel D (per step): logits[b,v] = h[b,:]·Wout[:,v] + bout[v]; write fp32 to
// d_out; argmax via packed (key<<32 | 0x7FFFFFFF-v) u64 atomicMax (first-index
// tie rule). Grid (235 v-tiles x 2 b-halves) x 256 threads; h-half in LDS.
// ---------------------------------------------------------------------------
__global__ __launch_bounds__(256) void k_logits(
    const float* __restrict__ Wout, const float* __restrict__ bout,
    const float* __restrict__ h, float* __restrict__ outSeq,
    unsigned long long* __restrict__ packedCur, int step) {
  __shared__ float hl[32 * H];  // 64 KiB
  const int tid = threadIdx.x;
  const int bh = blockIdx.y;
  const int v0 = blockIdx.x * 128;
  for (int k = tid; k < 32 * H; k += 256) hl[k] = h[(size_t)bh * 32 * H + k];
  __syncthreads();
  const int vg = tid & 31, bg = tid >> 5;  // 32 v-groups x 8 b-groups(of 4)
  const int v = v0 + vg * 4;
  const bool act = v < NV;
  unsigned long long bestk[4] = {0ull, 0ull, 0ull, 0ull};
  if (act) {
    float acc[4][4];
    float4 bo = *(const float4*)(bout + v);
#pragma unroll
    for (int r = 0; r < 4; ++r) {
      acc[r][0] = bo.x; acc[r][1] = bo.y; acc[r][2] = bo.z; acc[r][3] = bo.w;
    }
    const float* wp = Wout + v;
    const float* hp = hl + bg * 4 * H;
#pragma unroll 2
    for (int j = 0; j < H; ++j) {
      float4 w = *(const float4*)wp;
#pragma unroll
      for (int r = 0; r < 4; ++r) {
        float hv = hp[r * H + j];
        acc[r][0] += hv * w.x; acc[r][1] += hv * w.y;
        acc[r][2] += hv * w.z; acc[r][3] += hv * w.w;
      }
      wp += NV;
    }
#pragma unroll
    for (int r = 0; r < 4; ++r) {
      int b = bh * 32 + bg * 4 + r;
      size_t off = ((size_t)b * NSTEP + step) * NV + v;
      *(float4*)(outSeq + off) = make_float4(acc[r][0], acc[r][1], acc[r][2], acc[r][3]);
#pragma unroll
      for (int vv = 0; vv < 4; ++vv) {
        unsigned long long key = ((unsigned long long)fkey(acc[r][vv]) << 32)
                               | (unsigned long long)(0x7FFFFFFFu - (unsigned)(v + vv));
        if (key > bestk[r]) bestk[r] = key;
      }
    }
  }
  // reduce across the 32 v-group lanes (xor<32 stays within half-wave = fixed bg)
#pragma unroll
  for (int m = 16; m >= 1; m >>= 1) {
#pragma unroll
    for (int r = 0; r < 4; ++r) {
      unsigned long long o = __shfl_xor(bestk[r], m, 64);
      if (o > bestk[r]) bestk[r] = o;
    }
  }
  if (vg == 0) {
#pragma unroll
    for (int r = 0; r < 4; ++r)
      atomicMax(&packedCur[bh * 32 + bg * 4 + r], bestk[r]);
  }
}

// Final prediction (step 26) from last packed argmax.
__global__ void k_predfinal(const unsigned long long* __restrict__ packed,
                            float* __restrict__ pred) {
  const int b = threadIdx.x;
  int v = 0x7FFFFFFF - (int)(unsigned)(packed[b] & 0xFFFFFFFFull);
  pred[b * NSTEP + (NSTEP - 1)] = (float)v;
}

// ---------------------------------------------------------------------------
extern "C" void kernel_launch(void* const* d_in, const int* in_sizes, int n_in,
                              void* d_out, int out_size, void* d_ws, size_t ws_size,
                              hipStream_t stream) {
  (void)in_sizes; (void)n_in; (void)out_size; (void)ws_size;
  const float* encLast = (const float*)d_in[0];   // (1,B,H)
  const float* enc     = (const float*)d_in[1];   // (B,S,H)
  const float* emb     = (const float*)d_in[4];   // (V,WD)
  const float* W1      = (const float*)d_in[5];
  const float* W2      = (const float*)d_in[7];
  const float* W3      = (const float*)d_in[9];
  const float* Wv      = (const float*)d_in[11];
  const float* Wih     = (const float*)d_in[12];  // (1536,2048)
  const float* Whh     = (const float*)d_in[13];  // (512,2048)
  const float* bih     = (const float*)d_in[14];
  const float* bhh     = (const float*)d_in[15];
  const float* Wout    = (const float*)d_in[16];  // (512,30000)
  const float* bout    = (const float*)d_in[17];
  // b1/b2/b3 (d_in[6,8,10]) cancel in softmax; targets/tr_steps unused.

  float* wsf = (float*)d_ws;
  float* ue   = wsf;                // 512
  float* ctx  = wsf + 512;          // 64*512
  float* gctx = wsf + 33280;        // 64*2048
  float* hb0  = wsf + 164352;       // 64*512
  float* hb1  = wsf + 197120;       // 64*512
  float* cbuf = wsf + 229888;       // 64*512
  unsigned long long* packed = (unsigned long long*)(wsf + 262656);  // 27*64 u64

  float* outSeq = (float*)d_out;                        // fp32 seq [B,27,V]
  float* pred   = outSeq + (size_t)NB * NSTEP * NV;     // fp32 preds [B,27]

  k_ue  <<<1, 512, 0, stream>>>(W1, W2, W3, Wv, ue);
  k_attn<<<NB, 256, 0, stream>>>(enc, ue, ctx);
  k_gctx<<<64, 256, 0, stream>>>(Wih, bih, bhh, ctx, gctx);

  for (int t = 0; t < NSTEP; ++t) {
    const float* hin = (t == 0) ? encLast : ((t & 1) ? hb0 : hb1);
    float* hout = (t & 1) ? hb1 : hb0;
    const unsigned long long* pprev = packed + (t > 0 ? (size_t)(t - 1) * NB : 0);
    k_step<<<256, 256, 0, stream>>>(emb, Wih, Whh, gctx, hin, hout, cbuf,
                                    pprev, packed + (size_t)t * NB, pred, t);
    k_logits<<<dim3(235, 2), 256, 0, stream>>>(Wout, bout, hout, outSeq,
                                               packed + (size_t)t * NB, t);
  }
  k_predfinal<<<1, NB, 0, stream>>>(packed + (size_t)(NSTEP - 1) * NB, pred);
}